// Round 2
// baseline (451.772 us; speedup 1.0000x reference)
//
#include <hip/hip_runtime.h>
#include <stdint.h>

#define cN0 100000
#define cN1 150000
#define cN2 50000
#define cNNZ00 1600000
#define cNNZ12 200000
#define cD 128

#define BROWS_LOG 9
#define BROWS 512
#define CAP00 10240   // bucket slab capacity graph 0->0 (mean 8192, sigma~90)
#define CAP12 3072    // bucket slab capacity graph 1->2 (mean 2041, sigma~45)
#define NB0 196       // ceil(cN0/512)
#define NB2 98        // ceil(cN2/512)

#define PBLK 4096
#define PB0n ((cNNZ00 + PBLK - 1) / PBLK)   // 391
#define PB1n ((cNNZ12 + PBLK - 1) / PBLK)   // 49

#define T1 ((cN1 + 127) / 128)              // 1172 row-tiles of x1
#define T0 ((cN0 + 127) / 128)              // 782  row-tiles of x0
#define NGB1 293                            // persistent blocks for x1 (4 tiles each)
#define NGB0 196                            // persistent blocks for x0 (~4 tiles each)

typedef __attribute__((ext_vector_type(8))) short short8;
typedef __attribute__((ext_vector_type(4))) float f32x4;

__device__ __forceinline__ uint16_t f2bf(float f) {
    uint32_t u = __float_as_uint(f);
    u += 0x7fffu + ((u >> 16) & 1u);
    return (uint16_t)(u >> 16);
}
__device__ __forceinline__ float bf2f(uint32_t lo16) {
    return __uint_as_float(lo16 << 16);
}

// ---------------- Prepack: W (fp32) -> MFMA-fragment-ordered bf16, ONCE ------
// block 0: W0 -> P0 (+ zero the 512 bucket cursors); block 1: W12 -> P12
__global__ __launch_bounds__(256) void prepack_kernel(
    const float* __restrict__ W0, const float* __restrict__ W12,
    uint16_t* __restrict__ P0, uint16_t* __restrict__ P12,
    int* __restrict__ bcur)   // bcur0[256] followed by bcur2[256]
{
    const int tid = threadIdx.x;
    if (blockIdx.x == 0) { bcur[tid] = 0; bcur[tid + 256] = 0; }
    const float* W = blockIdx.x ? W12 : W0;
    uint16_t*    P = blockIdx.x ? P12 : P0;
    for (int i = tid * 4; i < cD * cD; i += 1024) {
        int k = i >> 7, c = i & 127;
        float4 w = *(const float4*)&W[i];
        int kt = k >> 5, q = (k >> 3) & 3, j = k & 7;
        uint16_t b[4] = { f2bf(w.x), f2bf(w.y), f2bf(w.z), f2bf(w.w) };
        #pragma unroll
        for (int t = 0; t < 4; ++t) {
            int cc = c + t, ct = cc >> 4, n = cc & 15;
            P[(((kt * 8 + ct) * 64) + q * 16 + n) * 8 + j] = b[t];
        }
    }
}

// ---------------- Mega dispatch: persistent GEMM blocks + partition blocks ---
// blocks [0, NGB1)            : x1@W12 tiles (grid-stride), write h12 + relu1
// blocks [NGB1, NGB1+NGB0)    : x0@W0 tiles (grid-stride), write h0
// blocks [NGB1+NGB0, +PB0n+PB1n): edge partition into fixed-capacity slabs
__global__ __launch_bounds__(256) void mega_kernel(
    const float* __restrict__ x1, const uint16_t* __restrict__ P12,
    uint16_t* __restrict__ h12, float* __restrict__ relu1,
    const float* __restrict__ x0, const uint16_t* __restrict__ P0,
    uint16_t* __restrict__ h0,
    const int* __restrict__ r00, const int* __restrict__ c00, const float* __restrict__ v00,
    const int* __restrict__ r12, const int* __restrict__ c12, const float* __restrict__ v12,
    int* __restrict__ bcur0, int* __restrict__ bcur2,
    uint2* __restrict__ slab0, uint2* __restrict__ slab2)
{
    __shared__ __align__(16) char smem[40960];
    const int tid = threadIdx.x;
    const int bx  = blockIdx.x;

    if (bx < NGB1 + NGB0) {
        // ================= GEMM (persistent, pack-free) =================
        const float* x; const uint16_t* P; uint16_t* h; float* relu_out;
        int nrows, ntiles, tg, tstr; bool wr;
        if (bx < NGB1) {
            x = x1; P = P12; h = h12; relu_out = relu1; nrows = cN1;
            ntiles = T1; tg = bx; tstr = NGB1; wr = true;
        } else {
            x = x0; P = P0; h = h0; relu_out = nullptr; nrows = cN0;
            ntiles = T0; tg = bx - NGB1; tstr = NGB0; wr = false;
        }

        uint16_t* Bpack = (uint16_t*)smem;   // 32 KB, contiguous b128 copies
        for (int i = tid; i < 2048; i += 256)
            *(float4*)&Bpack[(size_t)i * 8] = *(const float4*)&P[(size_t)i * 8];
        __syncthreads();   // only sync in the whole block lifetime

        const int wid = tid >> 6, l = tid & 63;
        const int m = l & 15, q = l >> 4;

        for (int t = tg; t < ntiles; t += tstr) {
            const int rb = t * 128 + wid * 32;
            const int r0 = rb + m, r1 = rb + 16 + m;

            f32x4 acc[2][8];
            #pragma unroll
            for (int rt = 0; rt < 2; ++rt)
                #pragma unroll
                for (int ct = 0; ct < 8; ++ct)
                    acc[rt][ct] = (f32x4){0.f, 0.f, 0.f, 0.f};

            #pragma unroll
            for (int kt = 0; kt < 4; ++kt) {
                const int k0 = kt * 32 + q * 8;
                float4 xa0 = make_float4(0.f,0.f,0.f,0.f), xa1 = xa0;
                float4 xb0 = xa0, xb1 = xa0;
                if (r0 < nrows) {
                    xa0 = *(const float4*)&x[(size_t)r0 * cD + k0];
                    xa1 = *(const float4*)&x[(size_t)r0 * cD + k0 + 4];
                }
                if (r1 < nrows) {
                    xb0 = *(const float4*)&x[(size_t)r1 * cD + k0];
                    xb1 = *(const float4*)&x[(size_t)r1 * cD + k0 + 4];
                }
                xa0.x=fmaxf(xa0.x,0.f); xa0.y=fmaxf(xa0.y,0.f); xa0.z=fmaxf(xa0.z,0.f); xa0.w=fmaxf(xa0.w,0.f);
                xa1.x=fmaxf(xa1.x,0.f); xa1.y=fmaxf(xa1.y,0.f); xa1.z=fmaxf(xa1.z,0.f); xa1.w=fmaxf(xa1.w,0.f);
                xb0.x=fmaxf(xb0.x,0.f); xb0.y=fmaxf(xb0.y,0.f); xb0.z=fmaxf(xb0.z,0.f); xb0.w=fmaxf(xb0.w,0.f);
                xb1.x=fmaxf(xb1.x,0.f); xb1.y=fmaxf(xb1.y,0.f); xb1.z=fmaxf(xb1.z,0.f); xb1.w=fmaxf(xb1.w,0.f);
                if (wr) {
                    if (r0 < nrows) {
                        *(float4*)&relu_out[(size_t)r0 * cD + k0]     = xa0;
                        *(float4*)&relu_out[(size_t)r0 * cD + k0 + 4] = xa1;
                    }
                    if (r1 < nrows) {
                        *(float4*)&relu_out[(size_t)r1 * cD + k0]     = xb0;
                        *(float4*)&relu_out[(size_t)r1 * cD + k0 + 4] = xb1;
                    }
                }
                short8 a0, a1;
                a0[0]=(short)f2bf(xa0.x); a0[1]=(short)f2bf(xa0.y); a0[2]=(short)f2bf(xa0.z); a0[3]=(short)f2bf(xa0.w);
                a0[4]=(short)f2bf(xa1.x); a0[5]=(short)f2bf(xa1.y); a0[6]=(short)f2bf(xa1.z); a0[7]=(short)f2bf(xa1.w);
                a1[0]=(short)f2bf(xb0.x); a1[1]=(short)f2bf(xb0.y); a1[2]=(short)f2bf(xb0.z); a1[3]=(short)f2bf(xb0.w);
                a1[4]=(short)f2bf(xb1.x); a1[5]=(short)f2bf(xb1.y); a1[6]=(short)f2bf(xb1.z); a1[7]=(short)f2bf(xb1.w);

                #pragma unroll
                for (int ct = 0; ct < 8; ++ct) {
                    short8 bf = *(const short8*)&Bpack[((kt * 8 + ct) * 64 + l) * 8];
                    acc[0][ct] = __builtin_amdgcn_mfma_f32_16x16x32_bf16(a0, bf, acc[0][ct], 0, 0, 0);
                    acc[1][ct] = __builtin_amdgcn_mfma_f32_16x16x32_bf16(a1, bf, acc[1][ct], 0, 0, 0);
                }
            }

            #pragma unroll
            for (int rt = 0; rt < 2; ++rt) {
                #pragma unroll
                for (int i = 0; i < 4; ++i) {
                    int row = rb + rt * 16 + q * 4 + i;
                    if (row < nrows) {
                        #pragma unroll
                        for (int ct = 0; ct < 8; ++ct)
                            h[(size_t)row * cD + ct * 16 + m] = f2bf(acc[rt][ct][i]);
                    }
                }
            }
        }
    } else {
        // ================= Partition into fixed-capacity slabs =================
        uint2*   sedge   = (uint2*)smem;                 // 32 KB
        uint8_t* sbkt    = (uint8_t*)(smem + 32768);     //  4 KB
        int*     lcount  = (int*)(smem + 36864);
        int*     loffset = (int*)(smem + 37888);
        int*     lcur    = (int*)(smem + 38912);
        int*     gbase   = (int*)(smem + 39936);

        int pb = bx - (NGB1 + NGB0);
        const int* rows; const int* cols; const float* vals;
        int nnz, nb, cap, bb; int* bcur; uint2* out;
        if (pb < PB0n) {
            rows = r00; cols = c00; vals = v00; nnz = cNNZ00; nb = NB0; cap = CAP00;
            bcur = bcur0; out = slab0; bb = pb;
        } else {
            rows = r12; cols = c12; vals = v12; nnz = cNNZ12; nb = NB2; cap = CAP12;
            bcur = bcur2; out = slab2; bb = pb - PB0n;
        }
        const int base = bb * PBLK;
        const int count = min(PBLK, nnz - base);

        lcount[tid] = 0;
        __syncthreads();
        for (int i = tid; i < count; i += 256)
            atomicAdd(&lcount[rows[base + i] >> BROWS_LOG], 1);
        __syncthreads();

        int v = lcount[tid];
        loffset[tid] = v;
        __syncthreads();
        for (int o = 1; o < 256; o <<= 1) {
            int x = (tid >= o) ? loffset[tid - o] : 0;
            __syncthreads();
            loffset[tid] += x;
            __syncthreads();
        }
        int ex = loffset[tid] - v;
        __syncthreads();
        loffset[tid] = ex;
        lcur[tid] = ex;
        if (tid < nb && v > 0) gbase[tid] = atomicAdd(&bcur[tid], v);
        __syncthreads();

        for (int i = tid; i < count; i += 256) {
            int r = rows[base + i];
            uint32_t c = (uint32_t)cols[base + i];
            float w = vals[base + i];
            int b = r >> BROWS_LOG;
            int pos = atomicAdd(&lcur[b], 1);
            sedge[pos] = make_uint2(((uint32_t)(r & (BROWS - 1)) << 20) | c, __float_as_uint(w));
            sbkt[pos] = (uint8_t)b;
        }
        __syncthreads();

        for (int i = tid; i < count; i += 256) {
            int b = sbkt[i];
            int gpos = gbase[b] + (i - loffset[b]);
            if (gpos < cap)   // slab overflow guard (statistically unreachable)
                out[(size_t)b * cap + gpos] = sedge[i];
        }
    }
}

// ---------------- Fine sort: per-bucket counting sort, slab -> slabSorted ----
// No LDS edge staging (4 KB LDS -> high occupancy); ping-pong avoids the
// in-place read/write hazard. 512 threads = 8 waves per bucket.
__global__ __launch_bounds__(512) void fine_kernel(
    const int* __restrict__ bcur0, const int* __restrict__ bcur2,
    const uint2* __restrict__ in0, const uint2* __restrict__ in2,
    uint2* __restrict__ out0, uint2* __restrict__ out2,
    int* __restrict__ rss0, int* __restrict__ rse0,
    int* __restrict__ rss2, int* __restrict__ rse2)
{
    __shared__ int rcnt[BROWS];
    __shared__ int psc[BROWS];

    int b, n, cap; const uint2* ein; uint2* eout; const int* bcur; int* rss; int* rse;
    if ((int)blockIdx.x < NB0) {
        b = blockIdx.x; ein = in0; eout = out0; bcur = bcur0; rss = rss0; rse = rse0;
        n = cN0; cap = CAP00;
    } else {
        b = blockIdx.x - NB0; ein = in2; eout = out2; bcur = bcur2; rss = rss2; rse = rse2;
        n = cN2; cap = CAP12;
    }
    const int tid = threadIdx.x;
    const int s = b * cap;
    const int count = min(bcur[b], cap);
    const int lo = b << BROWS_LOG;
    const int nr = min(BROWS, n - lo);

    rcnt[tid] = 0;
    __syncthreads();
    for (int i = tid; i < count; i += 512)
        atomicAdd(&rcnt[ein[s + i].x >> 20], 1);
    __syncthreads();

    int v = rcnt[tid];
    psc[tid] = v;
    __syncthreads();
    for (int o = 1; o < 512; o <<= 1) {
        int x = (tid >= o) ? psc[tid - o] : 0;
        __syncthreads();
        psc[tid] += x;
        __syncthreads();
    }
    int ex = psc[tid] - v;
    if (tid < nr) {
        rss[lo + tid] = s + ex;
        rse[lo + tid] = s + ex + v;
    }
    __syncthreads();
    rcnt[tid] = ex;
    __syncthreads();

    for (int i = tid; i < count; i += 512) {
        uint2 ed = ein[s + i];
        int rl = ed.x >> 20;
        int pos = atomicAdd(&rcnt[rl], 1);
        eout[s + pos] = make_uint2(ed.x & 0xFFFFFu, ed.y);
    }
}

// ---------------- Fused pull: y[r] = relu(sum_e val*h[col]), 1 wave / row ----
__global__ __launch_bounds__(256) void pull_fused(
    const int* __restrict__ rss2, const int* __restrict__ rse2,
    const uint2* __restrict__ slab2, const uint16_t* __restrict__ h12,
    float* __restrict__ y2,
    const int* __restrict__ rss0, const int* __restrict__ rse0,
    const uint2* __restrict__ slab0, const uint16_t* __restrict__ h0,
    float* __restrict__ y0,
    int wbase, int wcount)
{
    int wi = (blockIdx.x * 256 + threadIdx.x) >> 6;
    if (wi >= wcount) return;
    int w = wbase + wi;
    int l = threadIdx.x & 63;

    const int* rss; const int* rse; const uint2* edges; const uint16_t* h;
    float* y; int r;
    if (w < cN2) {
        rss = rss2; rse = rse2; edges = slab2; h = h12; y = y2; r = w;
    } else {
        rss = rss0; rse = rse0; edges = slab0; h = h0; y = y0; r = w - cN2;
    }

    int s = rss[r], e = rse[r];
    float a0 = 0.f, a1 = 0.f;
    int i = s;
    for (; i + 3 < e; i += 4) {
        uint2 e0 = edges[i], e1 = edges[i + 1], e2 = edges[i + 2], e3 = edges[i + 3];
        uint32_t p0 = *(const uint32_t*)&h[(size_t)e0.x * cD + l * 2];
        uint32_t p1 = *(const uint32_t*)&h[(size_t)e1.x * cD + l * 2];
        uint32_t p2 = *(const uint32_t*)&h[(size_t)e2.x * cD + l * 2];
        uint32_t p3 = *(const uint32_t*)&h[(size_t)e3.x * cD + l * 2];
        float v0 = __uint_as_float(e0.y), v1 = __uint_as_float(e1.y);
        float v2 = __uint_as_float(e2.y), v3 = __uint_as_float(e3.y);
        a0 = fmaf(v0, bf2f(p0 & 0xffffu), a0); a1 = fmaf(v0, bf2f(p0 >> 16), a1);
        a0 = fmaf(v1, bf2f(p1 & 0xffffu), a0); a1 = fmaf(v1, bf2f(p1 >> 16), a1);
        a0 = fmaf(v2, bf2f(p2 & 0xffffu), a0); a1 = fmaf(v2, bf2f(p2 >> 16), a1);
        a0 = fmaf(v3, bf2f(p3 & 0xffffu), a0); a1 = fmaf(v3, bf2f(p3 >> 16), a1);
    }
    for (; i < e; ++i) {
        uint2 ed = edges[i];
        uint32_t p = *(const uint32_t*)&h[(size_t)ed.x * cD + l * 2];
        float v = __uint_as_float(ed.y);
        a0 = fmaf(v, bf2f(p & 0xffffu), a0);
        a1 = fmaf(v, bf2f(p >> 16), a1);
    }
    *(float2*)&y[(size_t)r * cD + l * 2] = make_float2(fmaxf(a0, 0.f), fmaxf(a1, 0.f));
}

extern "C" void kernel_launch(void* const* d_in, const int* in_sizes, int n_in,
                              void* d_out, int out_size, void* d_ws, size_t ws_size,
                              hipStream_t stream) {
    const float* x0  = (const float*)d_in[0];
    const float* x1  = (const float*)d_in[1];
    const int*   r00 = (const int*)d_in[2];
    const int*   c00 = (const int*)d_in[3];
    const float* v00 = (const float*)d_in[4];
    const int*   r12 = (const int*)d_in[5];
    const int*   c12 = (const int*)d_in[6];
    const float* v12 = (const float*)d_in[7];
    const float* W0  = (const float*)d_in[8];
    const float* W12 = (const float*)d_in[9];

    float* out  = (float*)d_out;
    float* y0   = out;
    float* out1 = out + (size_t)cN0 * cD;
    float* y2   = out + (size_t)(cN0 + cN1) * cD;

    char* ws = (char*)d_ws;
    size_t o = 0;
    uint16_t* h0     = (uint16_t*)(ws + o); o += (size_t)cN0 * cD * 2;       // 25.6 MB
    uint2*    slab0  = (uint2*)   (ws + o); o += (size_t)NB0 * CAP00 * 8;    // 16.06 MB
    uint2*    slab2  = (uint2*)   (ws + o); o += (size_t)NB2 * CAP12 * 8;    // 2.41 MB
    uint2*    slabS0 = (uint2*)   (ws + o); o += (size_t)NB0 * CAP00 * 8;    // 16.06 MB
    uint2*    slabS2 = (uint2*)   (ws + o); o += (size_t)NB2 * CAP12 * 8;    // 2.41 MB
    int*      rss0   = (int*)     (ws + o); o += (size_t)cN0 * 4;
    int*      rse0   = (int*)     (ws + o); o += (size_t)cN0 * 4;
    int*      rss2   = (int*)     (ws + o); o += (size_t)cN2 * 4;
    int*      rse2   = (int*)     (ws + o); o += (size_t)cN2 * 4;
    int*      bcur0  = (int*)     (ws + o); o += 256 * 4;                     // adjacent:
    int*      bcur2  = (int*)     (ws + o); o += 256 * 4;                     //  zeroed together
    uint16_t* P0     = (uint16_t*)(ws + o); o += 32768;
    uint16_t* P12    = (uint16_t*)(ws + o); o += 32768;
    size_t o_h12 = o;
    size_t need_h12 = o_h12 + (size_t)cN1 * cD * 2;                           // ~103 MB total

    bool h12_in_ws = (ws_size >= need_h12);
    uint16_t* h12 = h12_in_ws ? (uint16_t*)(ws + o_h12) : (uint16_t*)y0;

    // 1. pack both W matrices once + zero bucket cursors (replaces memset)
    prepack_kernel<<<2, 256, 0, stream>>>(W0, W12, P0, P12, bcur0);

    // 2. mega: persistent GEMM blocks + partition blocks, one dispatch
    mega_kernel<<<NGB1 + NGB0 + PB0n + PB1n, 256, 0, stream>>>(
        x1, P12, h12, out1, x0, P0, h0,
        r00, c00, v00, r12, c12, v12,
        bcur0, bcur2, slab0, slab2);

    // 3. per-bucket counting sort (slab -> slabSorted)
    fine_kernel<<<NB0 + NB2, 512, 0, stream>>>(
        bcur0, bcur2, slab0, slab2, slabS0, slabS2,
        rss0, rse0, rss2, rse2);

    // 4. pull(s)
    if (h12_in_ws) {
        int wtot = cN2 + cN0;
        pull_fused<<<(wtot + 3) / 4, 256, 0, stream>>>(
            rss2, rse2, slabS2, h12, y2, rss0, rse0, slabS0, h0, y0, 0, wtot);
    } else {
        pull_fused<<<(cN2 + 3) / 4, 256, 0, stream>>>(
            rss2, rse2, slabS2, h12, y2, rss0, rse0, slabS0, h0, y0, 0, cN2);
        pull_fused<<<(cN0 + 3) / 4, 256, 0, stream>>>(
            rss2, rse2, slabS2, h12, y2, rss0, rse0, slabS0, h0, y0, cN2, cN0);
    }
}

// Round 3
// 419.930 us; speedup vs baseline: 1.0758x; 1.0758x over previous
//
#include <hip/hip_runtime.h>
#include <stdint.h>

#define cN0 100000
#define cN1 150000
#define cN2 50000
#define cNNZ00 1600000
#define cNNZ12 200000
#define cD 128

#define BROWS_LOG 9
#define BROWS 512
#define CAP00 10240   // bucket slab capacity graph 0->0 (mean 8192, sigma~90)
#define CAP12 3072    // bucket slab capacity graph 1->2 (mean 2041, sigma~45)
#define NB0 196       // ceil(cN0/512)
#define NB2 98        // ceil(cN2/512)

#define PBLK 3072
#define PB0n ((cNNZ00 + PBLK - 1) / PBLK)   // 521
#define PB1n ((cNNZ12 + PBLK - 1) / PBLK)   // 66

#define GB1 ((cN1 + 63) / 64)               // 2344 (64 rows / block, 16 / wave)
#define GB0 ((cN0 + 63) / 64)               // 1563

typedef __attribute__((ext_vector_type(8))) short short8;
typedef __attribute__((ext_vector_type(4))) float f32x4;

__device__ __forceinline__ uint16_t f2bf(float f) {
    uint32_t u = __float_as_uint(f);
    u += 0x7fffu + ((u >> 16) & 1u);
    return (uint16_t)(u >> 16);
}
__device__ __forceinline__ float bf2f(uint32_t lo16) {
    return __uint_as_float(lo16 << 16);
}

// ---------------- Prepack: W (fp32) -> MFMA-fragment-ordered bf16, ONCE ------
// block 0: W0 -> P0 (+ zero the 512 bucket cursors); block 1: W12 -> P12
__global__ __launch_bounds__(256) void prepack_kernel(
    const float* __restrict__ W0, const float* __restrict__ W12,
    uint16_t* __restrict__ P0, uint16_t* __restrict__ P12,
    int* __restrict__ bcur)   // bcur0[256] followed by bcur2[256]
{
    const int tid = threadIdx.x;
    if (blockIdx.x == 0) { bcur[tid] = 0; bcur[tid + 256] = 0; }
    const float* W = blockIdx.x ? W12 : W0;
    uint16_t*    P = blockIdx.x ? P12 : P0;
    for (int i = tid * 4; i < cD * cD; i += 1024) {
        int k = i >> 7, c = i & 127;
        float4 w = *(const float4*)&W[i];
        int kt = k >> 5, q = (k >> 3) & 3, j = k & 7;
        uint16_t b[4] = { f2bf(w.x), f2bf(w.y), f2bf(w.z), f2bf(w.w) };
        #pragma unroll
        for (int t = 0; t < 4; ++t) {
            int cc = c + t, ct = cc >> 4, n = cc & 15;
            P[(((kt * 8 + ct) * 64) + q * 16 + n) * 8 + j] = b[t];
        }
    }
}

// ---------------- Mega dispatch: non-persistent GEMM blocks + partition ------
// blocks [0, GB1)        : x1@W12, 64 rows/block (16/wave), write h12 + relu1
// blocks [GB1, GB1+GB0)  : x0@W0, 64 rows/block, write h0
// blocks [GB1+GB0, ...)  : edge partition into fixed-capacity slabs
__global__ __launch_bounds__(256, 4) void mega_kernel(
    const float* __restrict__ x1, const uint16_t* __restrict__ P12,
    uint16_t* __restrict__ h12, float* __restrict__ relu1,
    const float* __restrict__ x0, const uint16_t* __restrict__ P0,
    uint16_t* __restrict__ h0,
    const int* __restrict__ r00, const int* __restrict__ c00, const float* __restrict__ v00,
    const int* __restrict__ r12, const int* __restrict__ c12, const float* __restrict__ v12,
    int* __restrict__ bcur0, int* __restrict__ bcur2,
    uint2* __restrict__ slab0, uint2* __restrict__ slab2)
{
    __shared__ __align__(16) char smem[32768];
    const int tid = threadIdx.x;
    const int bx  = blockIdx.x;

    if (bx < GB1 + GB0) {
        // ================= GEMM: 16 rows/wave, all-K loads up front =========
        const float* x; const uint16_t* P; uint16_t* h; float* relu_out;
        int nrows, bb; bool wr;
        if (bx < GB1) {
            x = x1; P = P12; h = h12; relu_out = relu1; nrows = cN1;
            bb = bx; wr = true;
        } else {
            x = x0; P = P0; h = h0; relu_out = nullptr; nrows = cN0;
            bb = bx - GB1; wr = false;
        }

        uint16_t* Bpack = (uint16_t*)smem;   // 32 KB, contiguous b128 copies
        for (int i = tid; i < 2048; i += 256)
            *(float4*)&Bpack[(size_t)i * 8] = *(const float4*)&P[(size_t)i * 8];

        const int wid = tid >> 6, l = tid & 63;
        const int m = l & 15, q = l >> 4;
        const int row = bb * 64 + wid * 16 + m;
        const bool rv = row < nrows;

        // issue ALL x loads for this row up front (8 x float4 = 128 B/lane)
        float4 xr[8];
        #pragma unroll
        for (int j = 0; j < 8; ++j) xr[j] = make_float4(0.f, 0.f, 0.f, 0.f);
        if (rv) {
            const float* xp = &x[(size_t)row * cD + q * 8];
            #pragma unroll
            for (int kt = 0; kt < 4; ++kt) {
                xr[2 * kt]     = *(const float4*)&xp[kt * 32];
                xr[2 * kt + 1] = *(const float4*)&xp[kt * 32 + 4];
            }
        }
        #pragma unroll
        for (int j = 0; j < 8; ++j) {
            xr[j].x = fmaxf(xr[j].x, 0.f); xr[j].y = fmaxf(xr[j].y, 0.f);
            xr[j].z = fmaxf(xr[j].z, 0.f); xr[j].w = fmaxf(xr[j].w, 0.f);
        }
        if (wr && rv) {
            float* rp = &relu_out[(size_t)row * cD + q * 8];
            #pragma unroll
            for (int kt = 0; kt < 4; ++kt) {
                *(float4*)&rp[kt * 32]     = xr[2 * kt];
                *(float4*)&rp[kt * 32 + 4] = xr[2 * kt + 1];
            }
        }
        short8 afr[4];
        #pragma unroll
        for (int kt = 0; kt < 4; ++kt) {
            afr[kt][0] = (short)f2bf(xr[2*kt].x);   afr[kt][1] = (short)f2bf(xr[2*kt].y);
            afr[kt][2] = (short)f2bf(xr[2*kt].z);   afr[kt][3] = (short)f2bf(xr[2*kt].w);
            afr[kt][4] = (short)f2bf(xr[2*kt+1].x); afr[kt][5] = (short)f2bf(xr[2*kt+1].y);
            afr[kt][6] = (short)f2bf(xr[2*kt+1].z); afr[kt][7] = (short)f2bf(xr[2*kt+1].w);
        }

        __syncthreads();   // Bpack ready

        f32x4 acc[8];
        #pragma unroll
        for (int ct = 0; ct < 8; ++ct) acc[ct] = (f32x4){0.f, 0.f, 0.f, 0.f};
        #pragma unroll
        for (int kt = 0; kt < 4; ++kt) {
            #pragma unroll
            for (int ct = 0; ct < 8; ++ct) {
                short8 bf = *(const short8*)&Bpack[((kt * 8 + ct) * 64 + l) * 8];
                acc[ct] = __builtin_amdgcn_mfma_f32_16x16x32_bf16(afr[kt], bf, acc[ct], 0, 0, 0);
            }
        }

        #pragma unroll
        for (int i = 0; i < 4; ++i) {
            int orow = bb * 64 + wid * 16 + q * 4 + i;
            if (orow < nrows) {
                #pragma unroll
                for (int ct = 0; ct < 8; ++ct)
                    h[(size_t)orow * cD + ct * 16 + m] = f2bf(acc[ct][i]);
            }
        }
    } else {
        // ================= Partition into fixed-capacity slabs ==============
        uint2*   sedge   = (uint2*)smem;                 // 24 KB
        uint8_t* sbkt    = (uint8_t*)(smem + 24576);     //  3 KB
        int*     lcount  = (int*)(smem + 27648);
        int*     loffset = (int*)(smem + 28672);
        int*     lcur    = (int*)(smem + 29696);
        int*     gbase   = (int*)(smem + 30720);

        int pb = bx - (GB1 + GB0);
        const int* rows; const int* cols; const float* vals;
        int nnz, nb, cap, bb; int* bcur; uint2* out;
        if (pb < PB0n) {
            rows = r00; cols = c00; vals = v00; nnz = cNNZ00; nb = NB0; cap = CAP00;
            bcur = bcur0; out = slab0; bb = pb;
        } else {
            rows = r12; cols = c12; vals = v12; nnz = cNNZ12; nb = NB2; cap = CAP12;
            bcur = bcur2; out = slab2; bb = pb - PB0n;
        }
        const int base = bb * PBLK;
        const int count = min(PBLK, nnz - base);

        lcount[tid] = 0;
        __syncthreads();
        for (int i = tid; i < count; i += 256)
            atomicAdd(&lcount[rows[base + i] >> BROWS_LOG], 1);
        __syncthreads();

        int v = lcount[tid];
        loffset[tid] = v;
        __syncthreads();
        for (int o = 1; o < 256; o <<= 1) {
            int x = (tid >= o) ? loffset[tid - o] : 0;
            __syncthreads();
            loffset[tid] += x;
            __syncthreads();
        }
        int ex = loffset[tid] - v;
        __syncthreads();
        loffset[tid] = ex;
        lcur[tid] = ex;
        if (tid < nb && v > 0) gbase[tid] = atomicAdd(&bcur[tid], v);
        __syncthreads();

        for (int i = tid; i < count; i += 256) {
            int r = rows[base + i];
            uint32_t c = (uint32_t)cols[base + i];
            float w = vals[base + i];
            int b = r >> BROWS_LOG;
            int pos = atomicAdd(&lcur[b], 1);
            sedge[pos] = make_uint2(((uint32_t)(r & (BROWS - 1)) << 20) | c, __float_as_uint(w));
            sbkt[pos] = (uint8_t)b;
        }
        __syncthreads();

        for (int i = tid; i < count; i += 256) {
            int b = sbkt[i];
            int gpos = gbase[b] + (i - loffset[b]);
            if (gpos < cap)   // slab overflow guard (statistically unreachable)
                out[(size_t)b * cap + gpos] = sedge[i];
        }
    }
}

// ---------------- Fine sort: per-bucket counting sort, slab -> slabSorted ----
// 4 KB LDS -> high occupancy; ping-pong avoids in-place hazard.
__global__ __launch_bounds__(512) void fine_kernel(
    const int* __restrict__ bcur0, const int* __restrict__ bcur2,
    const uint2* __restrict__ in0, const uint2* __restrict__ in2,
    uint2* __restrict__ out0, uint2* __restrict__ out2,
    int* __restrict__ rss0, int* __restrict__ rse0,
    int* __restrict__ rss2, int* __restrict__ rse2)
{
    __shared__ int rcnt[BROWS];
    __shared__ int psc[BROWS];

    int b, n, cap; const uint2* ein; uint2* eout; const int* bcur; int* rss; int* rse;
    if ((int)blockIdx.x < NB0) {
        b = blockIdx.x; ein = in0; eout = out0; bcur = bcur0; rss = rss0; rse = rse0;
        n = cN0; cap = CAP00;
    } else {
        b = blockIdx.x - NB0; ein = in2; eout = out2; bcur = bcur2; rss = rss2; rse = rse2;
        n = cN2; cap = CAP12;
    }
    const int tid = threadIdx.x;
    const int s = b * cap;
    const int count = min(bcur[b], cap);
    const int lo = b << BROWS_LOG;
    const int nr = min(BROWS, n - lo);

    rcnt[tid] = 0;
    __syncthreads();
    for (int i = tid; i < count; i += 512)
        atomicAdd(&rcnt[ein[s + i].x >> 20], 1);
    __syncthreads();

    int v = rcnt[tid];
    psc[tid] = v;
    __syncthreads();
    for (int o = 1; o < 512; o <<= 1) {
        int x = (tid >= o) ? psc[tid - o] : 0;
        __syncthreads();
        psc[tid] += x;
        __syncthreads();
    }
    int ex = psc[tid] - v;
    if (tid < nr) {
        rss[lo + tid] = s + ex;
        rse[lo + tid] = s + ex + v;
    }
    __syncthreads();
    rcnt[tid] = ex;
    __syncthreads();

    for (int i = tid; i < count; i += 512) {
        uint2 ed = ein[s + i];
        int rl = ed.x >> 20;
        int pos = atomicAdd(&rcnt[rl], 1);
        eout[s + pos] = make_uint2(ed.x & 0xFFFFFu, ed.y);
    }
}

// ---------------- Fused pull: y[r] = relu(sum_e val*h[col]), 1 wave / row ----
__global__ __launch_bounds__(256) void pull_fused(
    const int* __restrict__ rss2, const int* __restrict__ rse2,
    const uint2* __restrict__ slab2, const uint16_t* __restrict__ h12,
    float* __restrict__ y2,
    const int* __restrict__ rss0, const int* __restrict__ rse0,
    const uint2* __restrict__ slab0, const uint16_t* __restrict__ h0,
    float* __restrict__ y0,
    int wbase, int wcount)
{
    int wi = (blockIdx.x * 256 + threadIdx.x) >> 6;
    if (wi >= wcount) return;
    int w = wbase + wi;
    int l = threadIdx.x & 63;

    const int* rss; const int* rse; const uint2* edges; const uint16_t* h;
    float* y; int r;
    if (w < cN2) {
        rss = rss2; rse = rse2; edges = slab2; h = h12; y = y2; r = w;
    } else {
        rss = rss0; rse = rse0; edges = slab0; h = h0; y = y0; r = w - cN2;
    }

    int s = rss[r], e = rse[r];
    float a0 = 0.f, a1 = 0.f;
    int i = s;
    for (; i + 3 < e; i += 4) {
        uint2 e0 = edges[i], e1 = edges[i + 1], e2 = edges[i + 2], e3 = edges[i + 3];
        uint32_t p0 = *(const uint32_t*)&h[(size_t)e0.x * cD + l * 2];
        uint32_t p1 = *(const uint32_t*)&h[(size_t)e1.x * cD + l * 2];
        uint32_t p2 = *(const uint32_t*)&h[(size_t)e2.x * cD + l * 2];
        uint32_t p3 = *(const uint32_t*)&h[(size_t)e3.x * cD + l * 2];
        float v0 = __uint_as_float(e0.y), v1 = __uint_as_float(e1.y);
        float v2 = __uint_as_float(e2.y), v3 = __uint_as_float(e3.y);
        a0 = fmaf(v0, bf2f(p0 & 0xffffu), a0); a1 = fmaf(v0, bf2f(p0 >> 16), a1);
        a0 = fmaf(v1, bf2f(p1 & 0xffffu), a0); a1 = fmaf(v1, bf2f(p1 >> 16), a1);
        a0 = fmaf(v2, bf2f(p2 & 0xffffu), a0); a1 = fmaf(v2, bf2f(p2 >> 16), a1);
        a0 = fmaf(v3, bf2f(p3 & 0xffffu), a0); a1 = fmaf(v3, bf2f(p3 >> 16), a1);
    }
    for (; i < e; ++i) {
        uint2 ed = edges[i];
        uint32_t p = *(const uint32_t*)&h[(size_t)ed.x * cD + l * 2];
        float v = __uint_as_float(ed.y);
        a0 = fmaf(v, bf2f(p & 0xffffu), a0);
        a1 = fmaf(v, bf2f(p >> 16), a1);
    }
    *(float2*)&y[(size_t)r * cD + l * 2] = make_float2(fmaxf(a0, 0.f), fmaxf(a1, 0.f));
}

extern "C" void kernel_launch(void* const* d_in, const int* in_sizes, int n_in,
                              void* d_out, int out_size, void* d_ws, size_t ws_size,
                              hipStream_t stream) {
    const float* x0  = (const float*)d_in[0];
    const float* x1  = (const float*)d_in[1];
    const int*   r00 = (const int*)d_in[2];
    const int*   c00 = (const int*)d_in[3];
    const float* v00 = (const float*)d_in[4];
    const int*   r12 = (const int*)d_in[5];
    const int*   c12 = (const int*)d_in[6];
    const float* v12 = (const float*)d_in[7];
    const float* W0  = (const float*)d_in[8];
    const float* W12 = (const float*)d_in[9];

    float* out  = (float*)d_out;
    float* y0   = out;
    float* out1 = out + (size_t)cN0 * cD;
    float* y2   = out + (size_t)(cN0 + cN1) * cD;

    char* ws = (char*)d_ws;
    size_t o = 0;
    uint16_t* h0     = (uint16_t*)(ws + o); o += (size_t)cN0 * cD * 2;       // 25.6 MB
    uint2*    slab0  = (uint2*)   (ws + o); o += (size_t)NB0 * CAP00 * 8;    // 16.06 MB
    uint2*    slab2  = (uint2*)   (ws + o); o += (size_t)NB2 * CAP12 * 8;    // 2.41 MB
    uint2*    slabS0 = (uint2*)   (ws + o); o += (size_t)NB0 * CAP00 * 8;    // 16.06 MB
    uint2*    slabS2 = (uint2*)   (ws + o); o += (size_t)NB2 * CAP12 * 8;    // 2.41 MB
    int*      rss0   = (int*)     (ws + o); o += (size_t)cN0 * 4;
    int*      rse0   = (int*)     (ws + o); o += (size_t)cN0 * 4;
    int*      rss2   = (int*)     (ws + o); o += (size_t)cN2 * 4;
    int*      rse2   = (int*)     (ws + o); o += (size_t)cN2 * 4;
    int*      bcur0  = (int*)     (ws + o); o += 256 * 4;                     // adjacent:
    int*      bcur2  = (int*)     (ws + o); o += 256 * 4;                     //  zeroed together
    uint16_t* P0     = (uint16_t*)(ws + o); o += 32768;
    uint16_t* P12    = (uint16_t*)(ws + o); o += 32768;
    size_t o_h12 = o;
    size_t need_h12 = o_h12 + (size_t)cN1 * cD * 2;                           // ~103 MB total

    bool h12_in_ws = (ws_size >= need_h12);
    uint16_t* h12 = h12_in_ws ? (uint16_t*)(ws + o_h12) : (uint16_t*)y0;

    // 1. pack both W matrices once + zero bucket cursors (replaces memset)
    prepack_kernel<<<2, 256, 0, stream>>>(W0, W12, P0, P12, bcur0);

    // 2. mega: non-persistent GEMM blocks + partition blocks, one dispatch
    mega_kernel<<<GB1 + GB0 + PB0n + PB1n, 256, 0, stream>>>(
        x1, P12, h12, out1, x0, P0, h0,
        r00, c00, v00, r12, c12, v12,
        bcur0, bcur2, slab0, slab2);

    // 3. per-bucket counting sort (slab -> slabSorted)
    fine_kernel<<<NB0 + NB2, 512, 0, stream>>>(
        bcur0, bcur2, slab0, slab2, slabS0, slabS2,
        rss0, rse0, rss2, rse2);

    // 4. pull(s)
    if (h12_in_ws) {
        int wtot = cN2 + cN0;
        pull_fused<<<(wtot + 3) / 4, 256, 0, stream>>>(
            rss2, rse2, slabS2, h12, y2, rss0, rse0, slabS0, h0, y0, 0, wtot);
    } else {
        pull_fused<<<(cN2 + 3) / 4, 256, 0, stream>>>(
            rss2, rse2, slabS2, h12, y2, rss0, rse0, slabS0, h0, y0, 0, cN2);
        pull_fused<<<(cN0 + 3) / 4, 256, 0, stream>>>(
            rss2, rse2, slabS2, h12, y2, rss0, rse0, slabS0, h0, y0, cN2, cN0);
    }
}